// Round 16
// baseline (647.301 us; speedup 1.0000x reference)
//
#include <hip/hip_runtime.h>

// LSTM (B=8192, T=168, F=64, H=50) + MLP head, fused, f16 MFMA + fp32 state.
// Round 16: 4 independent barrier domains per CU. 1024 blocks x 256 thr
// (4 merged-role waves), each block owns 8 batch rows (A-frag rows 8-15 are
// duplicates of 0-7 -> harmless duplicate C rows). Before gates, the valid
// 8x16 cells per gate-tile are COMPACTED onto all 64 lanes (2 shfl_xor(32)
// + 2 selects per gate) -> per-CU gate-trans identical to r7, no waste.
// Each wave: units [W*16,W*16+16), both x@Wx and h@Wh (8+8 MFMA/step),
// 2 cells of merged-rcp exp2 gates, 2 b16 h-writes, 1 lgkm-barrier/step.
// Target <=128 VGPR -> 16 waves/CU -> 4 blocks (domains)/CU.

#define B_N 8192
#define T_N 168
#define F_N 64
#define H_N 50
#define HEAD_N 100
#define RS (T_N * F_N)  // 10752

typedef _Float16 f16x8 __attribute__((ext_vector_type(8)));
typedef _Float16 f16x4 __attribute__((ext_vector_type(4)));
typedef float    f32x4 __attribute__((ext_vector_type(4)));

#define LOG2E  1.4426950408889634f
#define LOG2E2 2.8853900817779268f
#define MFMA __builtin_amdgcn_mfma_f32_16x16x32_f16

// LDS-only barrier: drain own LDS ops, barrier, compiler fence both sides.
// vmcnt NOT drained: register-destined x prefetch stays in flight.
#define BAR()                                                        \
    do {                                                             \
        asm volatile("s_waitcnt lgkmcnt(0)" ::: "memory");           \
        __builtin_amdgcn_s_barrier();                                \
        asm volatile("" ::: "memory");                               \
    } while (0)

__device__ __forceinline__ float rcp_f(float v) { return __builtin_amdgcn_rcpf(v); }
#if __has_builtin(__builtin_amdgcn_exp2f)
__device__ __forceinline__ float exp2_f(float v) { return __builtin_amdgcn_exp2f(v); }
#else
__device__ __forceinline__ float exp2_f(float v) { return __expf(0.6931471805599453f * v); }
#endif

__device__ __forceinline__ f16x8 cvt8(f32x4 a, f32x4 b) {
    f16x8 r;
    #pragma unroll
    for (int j = 0; j < 4; ++j) { r[j] = (_Float16)a[j]; r[4 + j] = (_Float16)b[j]; }
    return r;
}

__launch_bounds__(256, 4)
__global__ void lstm_fused(const float* __restrict__ x,
                           const float* __restrict__ Wx,
                           const float* __restrict__ Wh,
                           const float* __restrict__ b,
                           const float* __restrict__ W1,
                           const float* __restrict__ b1,
                           const float* __restrict__ W2,
                           const float* __restrict__ b2,
                           float* __restrict__ out)
{
    // h buffer [row][unit] f16, stride 72 (2-way bank alias only), dbuf
    __shared__ alignas(16) _Float16 h_lds[2][8][72];
    __shared__ float hrelu[8][HEAD_N];

    const int tid  = threadIdx.x;      // 0..255
    const int lane = tid & 63;
    const int W    = tid >> 6;         // wave 0..3: units W*16..+16
    const int cc   = lane & 15;        // unit col / A-frag row (dup by &7)
    const int kg   = lane >> 4;        // k-group
    const int R0   = blockIdx.x * 8;   // 8 batch rows of this block
    const int u    = W * 16 + cc;      // unit index 0..63
    const bool uv  = (u < H_N);
    const int rr   = ((kg & 1) << 2) | (kg & 2);   // lane's gate rows: rr, rr+1

    // ---- weights (both sides per wave), VGPR-resident, exp2-prescaled ----
    f16x8 wxf[4][2], whf[4][2];
    float bg[4];
    #pragma unroll
    for (int g = 0; g < 4; ++g) {
        const float sc = (g == 2) ? LOG2E2 : LOG2E;   // g-gate: fold tanh's 2x
        bg[g] = uv ? b[g * H_N + u] * sc : 0.0f;
        #pragma unroll
        for (int ks = 0; ks < 2; ++ks) {
            f16x8 vx, vh;
            #pragma unroll
            for (int i = 0; i < 8; ++i) {
                int k = ks * 32 + kg * 8 + i;   // same k-map as A-frags
                vx[i] = (_Float16)(uv ? Wx[k * 200 + g * H_N + u] * sc : 0.0f);
                vh[i] = (_Float16)((uv && k < H_N) ? Wh[k * 200 + g * H_N + u] * sc : 0.0f);
            }
            wxf[g][ks] = vx;
            whf[g][ks] = vh;
        }
    }

    // zero h(0)
    for (int idx = tid; idx < 8 * 72; idx += 256)
        ((_Float16*)h_lds[0])[idx] = (_Float16)0.0f;

    // x A-frag loads: lane reads batch row R0+(cc&7), k-cols kg*8+{0..7,32..39}
    const float* xb = x + (size_t)(R0 + (cc & 7)) * RS + kg * 8;
    f32x4 xq0, xq1, xq2, xq3;          // x(t+1) in flight (1-deep)
    f32x4 zacc[4];                     // z accumulators [gate]
    float cst0 = 0.f, cst1 = 0.f;      // cell state, rows rr, rr+1

    {   // prologue: zacc = bias + x(0)@Wx ; xq = x(1)
        f32x4 t0 = *(const f32x4*)(xb + 0);
        f32x4 t1 = *(const f32x4*)(xb + 4);
        f32x4 t2 = *(const f32x4*)(xb + 32);
        f32x4 t3 = *(const f32x4*)(xb + 36);
        xq0 = *(const f32x4*)(xb + F_N + 0);
        xq1 = *(const f32x4*)(xb + F_N + 4);
        xq2 = *(const f32x4*)(xb + F_N + 32);
        xq3 = *(const f32x4*)(xb + F_N + 36);
        f16x8 xa0 = cvt8(t0, t1), xa1 = cvt8(t2, t3);
        #pragma unroll
        for (int g = 0; g < 4; ++g) {
            f32x4 a = {bg[g], bg[g], bg[g], bg[g]};
            a = MFMA(xa0, wxf[g][0], a, 0, 0, 0);
            zacc[g] = MFMA(xa1, wxf[g][1], a, 0, 0, 0);
        }
    }
    const float* xld = xb + 2 * F_N;   // next load: x(2)
    __syncthreads();                   // h(0) visible

    // compaction: valid cells (rows 0-7) live in lanes<32 regs 0-3; spread to
    // all 64 lanes at 2 cells/lane: lane(c,kg) handles rows rr=kg-dependent.
#define EXTRACT(g, n0, n1)                                                     \
    float n0, n1;                                                              \
    {                                                                          \
        float s2_ = __shfl_xor(zacc[g][2], 32);                                \
        float s3_ = __shfl_xor(zacc[g][3], 32);                                \
        n0 = (lane < 32) ? zacc[g][0] : s2_;                                   \
        n1 = (lane < 32) ? zacc[g][1] : s3_;                                   \
    }

    // gates: merged-rcp pairs, exp2 domain (weights prescaled; g by 2x)
#define GATE1(zi_, zf_, zg_, zo_, cvar, hdst)                                  \
    {                                                                          \
        float A_ = exp2_f(-(zi_));                                             \
        float Bv = exp2_f(-(zg_));                                             \
        float Fv = exp2_f(-(zf_));                                             \
        float sf_ = rcp_f(1.0f + Fv);                                          \
        float r1_ = rcp_f((1.0f + A_) * (1.0f + Bv));                          \
        float cn_ = fmaf(sf_, cvar, (1.0f - Bv) * r1_);                        \
        cvar = cn_;                                                            \
        float Cv = exp2_f(-(zo_));                                             \
        float eD_ = fminf(-LOG2E2 * cn_, 80.0f);                               \
        float Dv = exp2_f(eD_);                                                \
        float r2_ = rcp_f((1.0f + Cv) * (1.0f + Dv));                          \
        hdst = (_Float16)((1.0f - Dv) * r2_);                                  \
    }

    // Step t (P=t&1): read h(t) A-frags; z += h@Wh; compact; reinit zacc =
    // bias + x(t+1)@Wx (MFMA pipe overlaps gate trans); gates -> 2 cells;
    // write h(t+1) rows rr,rr+1 unit u; load x(t+2); ONE 4-wave barrier.
#define STEP(P, DO_LOAD, DO_XNEXT)                                             \
    {                                                                          \
        f16x8 ha0 = *reinterpret_cast<const f16x8*>(&h_lds[P][cc & 7][kg * 8]);      \
        f16x8 ha1 = *reinterpret_cast<const f16x8*>(&h_lds[P][cc & 7][32 + kg * 8]); \
        f16x8 xa0, xa1;                                                        \
        if (DO_XNEXT) { xa0 = cvt8(xq0, xq1); xa1 = cvt8(xq2, xq3); }          \
        _Pragma("unroll")                                                      \
        for (int g = 0; g < 4; ++g) {                                          \
            zacc[g] = MFMA(ha0, whf[g][0], zacc[g], 0, 0, 0);                  \
            zacc[g] = MFMA(ha1, whf[g][1], zacc[g], 0, 0, 0);                  \
        }                                                                      \
        EXTRACT(0, zi0, zi1)                                                   \
        EXTRACT(1, zf0, zf1)                                                   \
        EXTRACT(2, zg0, zg1)                                                   \
        EXTRACT(3, zo0, zo1)                                                   \
        if (DO_XNEXT) {                                                        \
            _Pragma("unroll")                                                  \
            for (int g = 0; g < 4; ++g) {                                      \
                f32x4 a = {bg[g], bg[g], bg[g], bg[g]};                        \
                a = MFMA(xa0, wxf[g][0], a, 0, 0, 0);                          \
                zacc[g] = MFMA(xa1, wxf[g][1], a, 0, 0, 0);                    \
            }                                                                  \
        }                                                                      \
        _Float16 h0_, h1_;                                                     \
        GATE1(zi0, zf0, zg0, zo0, cst0, h0_)                                   \
        GATE1(zi1, zf1, zg1, zo1, cst1, h1_)                                   \
        h_lds[P ^ 1][rr][u]     = h0_;                                         \
        h_lds[P ^ 1][rr + 1][u] = h1_;                                         \
        if (DO_LOAD) {                                                         \
            xq0 = *(const f32x4*)(xld + 0);                                    \
            xq1 = *(const f32x4*)(xld + 4);                                    \
            xq2 = *(const f32x4*)(xld + 32);                                   \
            xq3 = *(const f32x4*)(xld + 36);                                   \
            xld += F_N;                                                        \
        }                                                                      \
        BAR();                                                                 \
    }

    for (int it = 0; it < 82; ++it) {   // t = 0..163 (loads x(2)..x(165))
        STEP(0, 1, 1)
        STEP(1, 1, 1)
    }
    STEP(0, 1, 1)   // t=164: uses x(165), loads x(166)
    STEP(1, 1, 1)   // t=165: uses x(166), loads x(167)
    STEP(0, 0, 1)   // t=166: uses x(167)
    STEP(1, 0, 0)   // t=167: final h(168) -> h_lds[0]
#undef STEP
#undef GATE1
#undef EXTRACT

    __syncthreads();

    // ---- MLP head: relu(h@W1 + b1)@W2 + b2 + x[:, -1, 0] ------------------
    // h(168) in h_lds[0], [row][unit], rows 0..7.
    {
        const int r1 = tid & 7;          // 0..7
        const int u1 = tid >> 3;         // 0..31
        float hrow[H_N];
        #pragma unroll
        for (int hk = 0; hk < H_N; ++hk) hrow[hk] = (float)h_lds[0][r1][hk];
        for (int uu = u1; uu < HEAD_N; uu += 32) {
            float s = b1[uu];
            #pragma unroll
            for (int hk = 0; hk < H_N; ++hk)
                s = fmaf(hrow[hk], W1[hk * HEAD_N + uu], s);
            hrelu[r1][uu] = fmaxf(s, 0.0f);
        }
    }
    __syncthreads();
    {
        const int r2 = tid >> 5;        // 0..7
        const int p  = tid & 31;
        float s = 0.0f;
        for (int uu = p; uu < HEAD_N; uu += 32) s += hrelu[r2][uu] * W2[uu];
        #pragma unroll
        for (int off = 16; off > 0; off >>= 1) s += __shfl_xor(s, off, 32);
        if (p == 0) {
            float res = x[(size_t)(R0 + r2) * RS + (T_N - 1) * F_N + 0];
            out[R0 + r2] = s + b2[0] + res;
        }
    }
}

extern "C" void kernel_launch(void* const* d_in, const int* in_sizes, int n_in,
                              void* d_out, int out_size, void* d_ws, size_t ws_size,
                              hipStream_t stream) {
    const float* x  = (const float*)d_in[0];
    const float* Wx = (const float*)d_in[1];
    const float* Wh = (const float*)d_in[2];
    const float* b  = (const float*)d_in[3];
    const float* W1 = (const float*)d_in[4];
    const float* b1 = (const float*)d_in[5];
    const float* W2 = (const float*)d_in[6];
    const float* b2 = (const float*)d_in[7];
    float* out = (float*)d_out;

    lstm_fused<<<dim3(B_N / 8), dim3(256), 0, stream>>>(x, Wx, Wh, b, W1, b1, W2, b2, out);
}

// Round 17
// 150.960 us; speedup vs baseline: 4.2879x; 4.2879x over previous
//
#include <hip/hip_runtime.h>

// LSTM (B=8192, T=168, F=64, H=50) + MLP head, fused, f16 MFMA + fp32 state.
// Round 17: REVERT to round-15 champion (150.8 us). r16's 4-domain attempt
// spilled (VGPR capped 64 vs ~112 live; WRITE_SIZE 0->111MB scratch) and the
// domain arithmetic shows 4 domains/CU structurally requires the spill.
// Structure: producer/consumer wave split (waves 0-3 x-role, 4-7 h-role),
// merged-rcp exp2 gates, 1 lgkm-barrier/step, setprio on h-waves, h stored
// [unit][row] with f16x4 writes + ds_read_b64_tr_b16 transpose reads.
// 512 blocks x 512 threads, 2 blocks/CU.

#define B_N 8192
#define T_N 168
#define F_N 64
#define H_N 50
#define HEAD_N 100
#define ROWSTRIDE (T_N * F_N)  // 10752

typedef _Float16 f16x8 __attribute__((ext_vector_type(8)));
typedef _Float16 f16x4 __attribute__((ext_vector_type(4)));
typedef float    f32x4 __attribute__((ext_vector_type(4)));

#define LOG2E  1.4426950408889634f
#define LOG2E2 2.8853900817779268f

#define MFMA __builtin_amdgcn_mfma_f32_16x16x32_f16

// LDS-only barrier: drain own LDS ops, barrier, compiler fence both sides.
// vmcnt NOT drained: register-destined global prefetch stays in flight.
#define BAR()                                                        \
    do {                                                             \
        asm volatile("s_waitcnt lgkmcnt(0)" ::: "memory");           \
        __builtin_amdgcn_s_barrier();                                \
        asm volatile("" ::: "memory");                               \
    } while (0)

__device__ __forceinline__ float rcp_f(float v) { return __builtin_amdgcn_rcpf(v); }
#if __has_builtin(__builtin_amdgcn_exp2f)
__device__ __forceinline__ float exp2_f(float v) { return __builtin_amdgcn_exp2f(v); }
#else
__device__ __forceinline__ float exp2_f(float v) { return __expf(0.6931471805599453f * v); }
#endif

__launch_bounds__(512, 4)
__global__ void lstm_fused(const float* __restrict__ x,
                           const float* __restrict__ Wx,
                           const float* __restrict__ Wh,
                           const float* __restrict__ b,
                           const float* __restrict__ W1,
                           const float* __restrict__ b1,
                           const float* __restrict__ W2,
                           const float* __restrict__ b2,
                           float* __restrict__ out)
{
    __shared__ alignas(16) _Float16 xb[2][16][72];        // xb[t&1] = x(t)
    __shared__ alignas(128) _Float16 h_lds[2][64][16];    // [unit][row], dbuf
    __shared__ alignas(16) float axb[2][4][4][64][4];     // [P][tile][gate][lane][4]
    __shared__ float hrelu[16][HEAD_N];

    const int tid  = threadIdx.x;
    const int lane = tid & 63;
    const int w    = tid >> 6;         // 0..7; 0-3 x-waves, 4-7 h-waves
    const int ut   = w & 3;            // unit-tile (16 units each)
    const int rowA = lane & 15;        // A-frag row == C-frag col
    const int kg   = lane >> 4;        // k-group 0..3
    const int R0   = blockIdx.x * 16;  // batch rows of this block
    const int jl   = ut * 16 + rowA;   // unit index 0..63
    const bool jv  = (jl < H_N);

    // ---- role-specific weight fragments (VGPR-resident, exp2-prescaled) --
    f16x8 wxf[4][2], whf[4][2];
    float bg[4];
    if (w < 4) {
        #pragma unroll
        for (int g = 0; g < 4; ++g) {
            const float sc = (g == 2) ? LOG2E2 : LOG2E;
            bg[g] = jv ? b[g * H_N + jl] * sc : 0.0f;
            #pragma unroll
            for (int ks = 0; ks < 2; ++ks) {
                f16x8 v;
                #pragma unroll
                for (int i = 0; i < 8; ++i) {
                    int k = ks * 32 + kg * 8 + i;     // same k-map as A-frags
                    v[i] = (_Float16)(jv ? Wx[k * 200 + g * H_N + jl] * sc : 0.0f);
                }
                wxf[g][ks] = v;
            }
        }
    } else {
        #pragma unroll
        for (int g = 0; g < 4; ++g) {
            const float sc = (g == 2) ? LOG2E2 : LOG2E;
            #pragma unroll
            for (int ks = 0; ks < 2; ++ks) {
                f16x8 v;
                #pragma unroll
                for (int i = 0; i < 8; ++i) {
                    int k = ks * 32 + kg * 8 + i;
                    v[i] = (_Float16)((jv && k < H_N) ? Wh[k * 200 + g * H_N + jl] * sc : 0.0f);
                }
                whf[g][ks] = v;
            }
        }
    }

    float c0 = 0.f, c1 = 0.f, c2 = 0.f, c3 = 0.f;   // h-wave fp32 cell state

    // zero h(0) buffer 0 ([unit][row] = 1024 f16)
    for (int idx = tid; idx < 1024; idx += 512)
        ((_Float16*)h_lds[0])[idx] = (_Float16)0.0f;

    // x staging map (x-waves = tid 0..255): (row tid>>4, 4 floats), coalesced
    const int xr  = (tid >> 4) & 15;
    const int xf0 = (tid & 15) * 4;
    const float* xrow = x + (size_t)(R0 + xr) * ROWSTRIDE + xf0;
    f32x4 xpr0, xpr1;     // in-flight x rows: xpr[t&1] LDS-written at step t
    if (w < 4) {
        f32x4 v0 = *reinterpret_cast<const f32x4*>(xrow);
        f32x4 v1 = *reinterpret_cast<const f32x4*>(xrow + F_N);
        xpr0 = *reinterpret_cast<const f32x4*>(xrow + 2 * F_N);   // x(2)
        xpr1 = *reinterpret_cast<const f32x4*>(xrow + 3 * F_N);   // x(3)
        f16x4 a, c4;
        #pragma unroll
        for (int j = 0; j < 4; ++j) { a[j] = (_Float16)v0[j]; c4[j] = (_Float16)v1[j]; }
        *reinterpret_cast<f16x4*>(&xb[0][xr][xf0]) = a;   // x(0)
        *reinterpret_cast<f16x4*>(&xb[1][xr][xf0]) = c4;  // x(1)
    }
    const float* xld = xrow + 4 * F_N;   // next global load: x(4)
    __syncthreads();

    if (w < 4) {   // prologue: ax(0) = b + x(0)@Wx -> axb[0]
        f16x8 xa0 = *reinterpret_cast<const f16x8*>(&xb[0][rowA][kg * 8]);
        f16x8 xa1 = *reinterpret_cast<const f16x8*>(&xb[0][rowA][32 + kg * 8]);
        f32x4 a0 = {bg[0], bg[0], bg[0], bg[0]};
        f32x4 a1 = {bg[1], bg[1], bg[1], bg[1]};
        f32x4 a2 = {bg[2], bg[2], bg[2], bg[2]};
        f32x4 a3 = {bg[3], bg[3], bg[3], bg[3]};
        a0 = MFMA(xa0, wxf[0][0], a0, 0, 0, 0);
        a1 = MFMA(xa0, wxf[1][0], a1, 0, 0, 0);
        a2 = MFMA(xa0, wxf[2][0], a2, 0, 0, 0);
        a3 = MFMA(xa0, wxf[3][0], a3, 0, 0, 0);
        a0 = MFMA(xa1, wxf[0][1], a0, 0, 0, 0);
        a1 = MFMA(xa1, wxf[1][1], a1, 0, 0, 0);
        a2 = MFMA(xa1, wxf[2][1], a2, 0, 0, 0);
        a3 = MFMA(xa1, wxf[3][1], a3, 0, 0, 0);
        *reinterpret_cast<f32x4*>(&axb[0][ut][0][lane][0]) = a0;
        *reinterpret_cast<f32x4*>(&axb[0][ut][1][lane][0]) = a1;
        *reinterpret_cast<f32x4*>(&axb[0][ut][2][lane][0]) = a2;
        *reinterpret_cast<f32x4*>(&axb[0][ut][3][lane][0]) = a3;
    }
    __syncthreads();

    // tr-read base (validated r12/r13/r14): window = base + kg*256, lane slot
    // rowA*8; offsets {0,128,1024,1152} -> A-frag k = units {kg*8..+3, +4..+7,
    // 32+kg*8..+3, 32+kg*8+4..+7} for row = rowA. Buffers 2048 B apart.
    const uint32_t trbase0 =
        (uint32_t)(uintptr_t)(&h_lds[0][0][0]) + (kg << 8) + (rowA << 3);
    const uint32_t trbase1 = trbase0 + 2048;

    // gates v2: merged-rcp pairs, exp2 domain (weights prescaled; g by 2x).
#define GATE1(ii, cvar)                                                        \
    {                                                                          \
        float A_ = exp2_f(-zi[ii]);                                            \
        float B_ = exp2_f(-zg[ii]);                                            \
        float F_ = exp2_f(-zf[ii]);                                            \
        float sf_ = rcp_f(1.0f + F_);                                          \
        float r1_ = rcp_f((1.0f + A_) * (1.0f + B_));                          \
        float cn_ = fmaf(sf_, cvar, (1.0f - B_) * r1_);                        \
        cvar = cn_;                                                            \
        float C_ = exp2_f(-zo[ii]);                                            \
        float eD_ = fminf(-LOG2E2 * cn_, 80.0f);                               \
        float D_ = exp2_f(eD_);                                                \
        float r2_ = rcp_f((1.0f + C_) * (1.0f + D_));                          \
        ph[ii] = (_Float16)((1.0f - D_) * r2_);                                \
    }

#define XSTEP(P, DO_XW, DO_LOAD)                                               \
    {                                                                          \
        f16x8 xa0 = *reinterpret_cast<const f16x8*>(&xb[P ^ 1][rowA][kg * 8]);      \
        f16x8 xa1 = *reinterpret_cast<const f16x8*>(&xb[P ^ 1][rowA][32 + kg * 8]); \
        f32x4 a0 = {bg[0], bg[0], bg[0], bg[0]};                               \
        f32x4 a1 = {bg[1], bg[1], bg[1], bg[1]};                               \
        f32x4 a2 = {bg[2], bg[2], bg[2], bg[2]};                               \
        f32x4 a3 = {bg[3], bg[3], bg[3], bg[3]};                               \
        a0 = MFMA(xa0, wxf[0][0], a0, 0, 0, 0);                                \
        a1 = MFMA(xa0, wxf[1][0], a1, 0, 0, 0);                                \
        a2 = MFMA(xa0, wxf[2][0], a2, 0, 0, 0);                                \
        a3 = MFMA(xa0, wxf[3][0], a3, 0, 0, 0);                                \
        a0 = MFMA(xa1, wxf[0][1], a0, 0, 0, 0);                                \
        a1 = MFMA(xa1, wxf[1][1], a1, 0, 0, 0);                                \
        a2 = MFMA(xa1, wxf[2][1], a2, 0, 0, 0);                                \
        a3 = MFMA(xa1, wxf[3][1], a3, 0, 0, 0);                                \
        *reinterpret_cast<f32x4*>(&axb[P ^ 1][ut][0][lane][0]) = a0;           \
        *reinterpret_cast<f32x4*>(&axb[P ^ 1][ut][1][lane][0]) = a1;           \
        *reinterpret_cast<f32x4*>(&axb[P ^ 1][ut][2][lane][0]) = a2;           \
        *reinterpret_cast<f32x4*>(&axb[P ^ 1][ut][3][lane][0]) = a3;           \
        if (DO_XW) {                                                           \
            f16x4 xc;                                                          \
            xc[0] = (_Float16)xpr##P[0]; xc[1] = (_Float16)xpr##P[1];          \
            xc[2] = (_Float16)xpr##P[2]; xc[3] = (_Float16)xpr##P[3];          \
            *reinterpret_cast<f16x4*>(&xb[P][xr][xf0]) = xc;                   \
        }                                                                      \
        if (DO_LOAD) { xpr##P = *reinterpret_cast<const f32x4*>(xld); xld += F_N; } \
        BAR();                                                                 \
    }

    // h-wave step t (P=t&1): tr-read h(t); z = axb[P] + h(t)@Wh; gates;
    // h(t+1) -> h_lds[P^1][unit jl][rows kg*4..+4] as one f16x4 write.
#define HSTEP(P)                                                               \
    {                                                                          \
        __builtin_amdgcn_s_setprio(1);                                         \
        f16x4 t0, t1, t2, t3;                                                  \
        asm volatile("ds_read_b64_tr_b16 %0, %1"                               \
                     : "=v"(t0) : "v"(trbase##P) : "memory");                  \
        asm volatile("ds_read_b64_tr_b16 %0, %1 offset:128"                    \
                     : "=v"(t1) : "v"(trbase##P) : "memory");                  \
        asm volatile("ds_read_b64_tr_b16 %0, %1 offset:1024"                   \
                     : "=v"(t2) : "v"(trbase##P) : "memory");                  \
        asm volatile("ds_read_b64_tr_b16 %0, %1 offset:1152"                   \
                     : "=v"(t3) : "v"(trbase##P) : "memory");                  \
        f32x4 zi = *reinterpret_cast<const f32x4*>(&axb[P][ut][0][lane][0]);   \
        f32x4 zf = *reinterpret_cast<const f32x4*>(&axb[P][ut][1][lane][0]);   \
        f32x4 zg = *reinterpret_cast<const f32x4*>(&axb[P][ut][2][lane][0]);   \
        f32x4 zo = *reinterpret_cast<const f32x4*>(&axb[P][ut][3][lane][0]);   \
        asm volatile("s_waitcnt lgkmcnt(0)" ::: "memory");                     \
        __builtin_amdgcn_sched_barrier(0);                                     \
        f16x8 ha0 = __builtin_shufflevector(t0, t1, 0, 1, 2, 3, 4, 5, 6, 7);   \
        f16x8 ha1 = __builtin_shufflevector(t2, t3, 0, 1, 2, 3, 4, 5, 6, 7);   \
        zi = MFMA(ha0, whf[0][0], zi, 0, 0, 0);                                \
        zf = MFMA(ha0, whf[1][0], zf, 0, 0, 0);                                \
        zg = MFMA(ha0, whf[2][0], zg, 0, 0, 0);                                \
        zo = MFMA(ha0, whf[3][0], zo, 0, 0, 0);                                \
        zi = MFMA(ha1, whf[0][1], zi, 0, 0, 0);                                \
        zf = MFMA(ha1, whf[1][1], zf, 0, 0, 0);                                \
        zg = MFMA(ha1, whf[2][1], zg, 0, 0, 0);                                \
        zo = MFMA(ha1, whf[3][1], zo, 0, 0, 0);                                \
        f16x4 ph;                                                              \
        GATE1(0, c0)                                                           \
        GATE1(1, c1)                                                           \
        GATE1(2, c2)                                                           \
        GATE1(3, c3)                                                           \
        *reinterpret_cast<f16x4*>(&h_lds[P ^ 1][jl][kg * 4]) = ph;             \
        __builtin_amdgcn_s_setprio(0);                                         \
        BAR();                                                                 \
    }

    // Both role-loops execute EXACTLY 168 barriers (mirror structure).
    if (w < 4) {
        for (int it = 0; it < 82; ++it) {   // t = 0..163
            XSTEP(0, 1, 1)
            XSTEP(1, 1, 1)
        }
        XSTEP(0, 1, 0)   // t=164: ax(165), write x(166)
        XSTEP(1, 1, 0)   // t=165: ax(166), write x(167)
        XSTEP(0, 0, 0)   // t=166: ax(167)
        BAR();           // t=167: x-waves just sync
    } else {
        for (int it = 0; it < 82; ++it) {   // t = 0..163
            HSTEP(0)
            HSTEP(1)
        }
        HSTEP(0)   // t=164
        HSTEP(1)   // t=165
        HSTEP(0)   // t=166
        HSTEP(1)   // t=167: final h(168) -> h_lds[0]
    }
#undef XSTEP
#undef HSTEP
#undef GATE1

    // ---- MLP head: relu(h@W1 + b1)@W2 + b2 + x[:, -1, 0] ------------------
    // h(168) in h_lds[0], [unit][row] layout.
    if (tid < 256) {
        const int r1 = tid & 15;
        const int u1 = tid >> 4;
        float hrow[H_N];
        #pragma unroll
        for (int hk = 0; hk < H_N; ++hk) hrow[hk] = (float)h_lds[0][hk][r1];
        for (int uu = u1; uu < HEAD_N; uu += 16) {
            float s = b1[uu];
            #pragma unroll
            for (int hk = 0; hk < H_N; ++hk) s += hrow[hk] * W1[hk * HEAD_N + uu];
            hrelu[r1][uu] = fmaxf(s, 0.0f);
        }
    }
    __syncthreads();
    if (tid < 256) {
        const int r2 = tid >> 4;
        const int p  = tid & 15;
        float s = 0.0f;
        for (int uu = p; uu < HEAD_N; uu += 16) s += hrelu[r2][uu] * W2[uu];
        #pragma unroll
        for (int off = 8; off > 0; off >>= 1) s += __shfl_xor(s, off, 16);
        if (p == 0) {
            float res = x[(size_t)(R0 + r2) * ROWSTRIDE + (T_N - 1) * F_N + 0];
            out[R0 + r2] = s + b2[0] + res;
        }
    }
}

extern "C" void kernel_launch(void* const* d_in, const int* in_sizes, int n_in,
                              void* d_out, int out_size, void* d_ws, size_t ws_size,
                              hipStream_t stream) {
    const float* x  = (const float*)d_in[0];
    const float* Wx = (const float*)d_in[1];
    const float* Wh = (const float*)d_in[2];
    const float* b  = (const float*)d_in[3];
    const float* W1 = (const float*)d_in[4];
    const float* b1 = (const float*)d_in[5];
    const float* W2 = (const float*)d_in[6];
    const float* b2 = (const float*)d_in[7];
    float* out = (float*)d_out;

    lstm_fused<<<dim3(B_N / 16), dim3(512), 0, stream>>>(x, Wx, Wh, b, W1, b1, W2, b2, out);
}